// Round 13
// baseline (108.240 us; speedup 1.0000x reference)
//
#include <hip/hip_runtime.h>
#include <hip/hip_bf16.h>
#include <cstdint>
#include <cmath>

#define B_ 512
#define T_ 256
#define C_ 256
#define HS_ 64

typedef short bf16x8 __attribute__((ext_vector_type(8)));
typedef float f32x4 __attribute__((ext_vector_type(4)));

static __device__ __forceinline__ unsigned short f2bf(float f) {
    union { float f; unsigned int u; } v; v.f = f;
    unsigned int r = v.u + 0x7fffu + ((v.u >> 16) & 1u);
    return (unsigned short)(r >> 16);
}

static __device__ __forceinline__ uint2 pack4(f32x4 a) {
    uint2 r;
    r.x = (unsigned)f2bf(a[0]) | ((unsigned)f2bf(a[1]) << 16);
    r.y = (unsigned)f2bf(a[2]) | ((unsigned)f2bf(a[3]) << 16);
    return r;
}

// ---- Kernel 0: W -> pre-fragmented bf16 WTf.
// fb = fid*8 + kap ; fid = ws*4+f ; WTf[fb*512 + l*8 + j] = W_ws[kap*32+(l>>4)*8+j][f*16+(l&15)]
__global__ void wt_kernel(const float* __restrict__ Wq, const float* __restrict__ Wk,
                          const float* __restrict__ Wv, unsigned short* __restrict__ WTf) {
    int idx = blockIdx.x * 256 + threadIdx.x;
    if (idx >= 96 * 64) return;
    int fb = idx >> 6;
    int l = idx & 63;
    int ws = fb >> 5;
    int rem = fb & 31;
    int f = rem >> 3;
    int kap = rem & 7;
    const float* W = (ws == 0) ? Wq : ((ws == 1) ? Wk : Wv);
    unsigned short o[8];
#pragma unroll
    for (int j = 0; j < 8; ++j) {
        int k = kap * 32 + (l >> 4) * 8 + j;
        int n = f * 16 + (l & 15);
        o[j] = f2bf(W[k * HS_ + n]);
    }
    *(ulonglong2*)(WTf + (size_t)idx * 8) = *(ulonglong2*)o;
}

// Phase-2 granule LUT: wave w (SIMD = w%4) -> granule; per-SIMD kt sums all = 18.
__device__ __constant__ const int g_lut[16] = {15,14,11,9, 13,12,10,8, 1,0,4,6, 3,2,5,7};

// ---- Fused kernel: 256 blocks x 2 batches. 1024 threads / 16 waves. 160 KB LDS.
// Per batch: [0,96K) W (phase 1) -> Q/K/Vt (phase 2); [96K,160K) x slab / P tiles.
// Batch-1 slab-0 x prefetched into regs under batch-0 phase 2 (32 VGPR held).
__global__ __launch_bounds__(1024, 4)
void fused_kernel(const float* __restrict__ x, const unsigned short* __restrict__ WTf,
                  float* __restrict__ out) {
    __shared__ __align__(16) char smem[163840];
    unsigned short* Qs  = (unsigned short*)(smem);
    unsigned short* Ks  = (unsigned short*)(smem + 32768);
    unsigned short* Vts = (unsigned short*)(smem + 65536);
    char* xbuf = smem + 98304;

    const int tid = threadIdx.x;
    const int w = tid >> 6, l = tid & 63, ln = l & 15, lg = l >> 4;
    const int ttp = w & 3;          // tile-pair: tiles 2*ttp, 2*ttp+1
    const int fg  = w >> 2;         // fid-group: fids fg*3 .. fg*3+2
    const float scale = 0.0625f;    // C^-0.5

    float4 st[8];
    uint2 h0[6], h1[6];

#define LOADX(BASE) do { \
    _Pragma("unroll") \
    for (int i_ = 0; i_ < 8; ++i_) \
        st[i_] = *(const float4*)((BASE) + (size_t)(i_ * 1024 + tid) * 4); \
} while (0)

#define DS_WRITE_SLAB() do { \
    _Pragma("unroll") \
    for (int i_ = 0; i_ < 8; ++i_) { \
        const int fidx_ = i_ * 1024 + tid, row_ = fidx_ >> 6, c4_ = (fidx_ & 63) * 4; \
        ushort4 hh_; \
        hh_.x = f2bf(st[i_].x); hh_.y = f2bf(st[i_].y); \
        hh_.z = f2bf(st[i_].z); hh_.w = f2bf(st[i_].w); \
        *(ushort4*)(xbuf + row_ * 512 + ((c4_ * 2) ^ ((row_ & 7) << 4))) = hh_; \
    } \
} while (0)

#define SLAB_COMPUTE(H) do { \
    f32x4 acc_[6]; \
    _Pragma("unroll") \
    for (int k_ = 0; k_ < 6; ++k_) acc_[k_] = (f32x4){0.f, 0.f, 0.f, 0.f}; \
    _Pragma("unroll") \
    for (int kap_ = 0; kap_ < 8; ++kap_) { \
        bf16x8 bfr_[3]; \
        _Pragma("unroll") \
        for (int j_ = 0; j_ < 3; ++j_) \
            bfr_[j_] = *(const bf16x8*)(smem + (size_t)((fg * 3 + j_) * 8 + kap_) * 1024 + l * 16); \
        _Pragma("unroll") \
        for (int tt_ = 0; tt_ < 2; ++tt_) { \
            const int R_ = (2 * ttp + tt_) * 16 + ln; \
            bf16x8 afr_ = *(const bf16x8*)(xbuf + R_ * 512 \
                           + ((kap_ * 64 + lg * 16) ^ ((R_ & 7) << 4))); \
            _Pragma("unroll") \
            for (int j_ = 0; j_ < 3; ++j_) \
                acc_[tt_ * 3 + j_] = __builtin_amdgcn_mfma_f32_16x16x32_bf16( \
                    bfr_[j_], afr_, acc_[tt_ * 3 + j_], 0, 0, 0); \
        } \
    } \
    _Pragma("unroll") \
    for (int k_ = 0; k_ < 6; ++k_) H[k_] = pack4(acc_[k_]); \
} while (0)

    LOADX(x + (size_t)blockIdx.x * 65536);     // batch-0 slab-0 (issued before W gll)

    for (int bb = 0; bb < 2; ++bb) {
        const int b = blockIdx.x + bb * 256;
        const float* xb = x + (size_t)b * 65536;

        // ---- W -> LDS (linear dest); batch 1 hits warm per-XCD L2 ----
#pragma unroll
        for (int r = 0; r < 6; ++r)
            __builtin_amdgcn_global_load_lds(
                (const __attribute__((address_space(1))) void*)((const char*)WTf + r * 16384 + tid * 16),
                (__attribute__((address_space(3))) void*)(smem + r * 16384 + tid * 16), 16, 0, 0);

        // ---- slab 0 ----
        DS_WRITE_SLAB();            // waits st only (counted vmcnt); barrier drains W
        __syncthreads();
        LOADX(xb + 32768);          // slab-1 prefetch under slab-0 compute
        SLAB_COMPUTE(h0);
        __syncthreads();

        // ---- slab 1 ----
        DS_WRITE_SLAB();
        __syncthreads();
        SLAB_COMPUTE(h1);
        __syncthreads();            // all W-lds reads done; region reusable

        // ---- phase 1.5: QKV regs -> LDS (overwrites W region) ----
#pragma unroll
        for (int s = 0; s < 2; ++s) {
#pragma unroll
            for (int tt = 0; tt < 2; ++tt)
#pragma unroll
                for (int j = 0; j < 3; ++j) {
                    uint2 hv = s ? h1[tt * 3 + j] : h0[tt * 3 + j];
                    const int token = s * 128 + (2 * ttp + tt) * 16 + ln;
                    const int fid = fg * 3 + j, f = fid & 3;
                    if (fid < 8) {
                        unsigned short* base_ = (fid < 4) ? Qs : Ks;
                        *(uint2*)((char*)base_ + token * 128
                                  + ((f * 32 + lg * 8) ^ ((token & 7) << 4))) = hv;
                    } else {
                        unsigned short v4[4] = {
                            (unsigned short)(hv.x & 0xffff), (unsigned short)(hv.x >> 16),
                            (unsigned short)(hv.y & 0xffff), (unsigned short)(hv.y >> 16)};
#pragma unroll
                        for (int i = 0; i < 4; ++i) {
                            const int vr = f * 16 + lg * 4 + i;
                            *(unsigned short*)((char*)Vts + vr * 512
                                  + ((token * 2) ^ ((vr & 7) << 4))) = v4[i];
                        }
                    }
                }
        }
        __syncthreads();

        // batch-1 slab-0 prefetch: lands under batch-0 phase 2 (32 VGPR held)
        if (bb == 0)
            LOADX(x + ((size_t)blockIdx.x + 256) * 65536);

        // ---- phase 2: causal attention, swapped-QK^T; wave = ONE granule ----
        unsigned short* Pl = (unsigned short*)(xbuf + w * 1280);   // [16][40] per wave
        float* outb = out + (size_t)b * (T_ * HS_);

        {
            const int g = g_lut[w];
            const int r0 = g * 16;
            const int qrow = r0 + ln;

            bf16x8 qa[2];
#pragma unroll
            for (int kk = 0; kk < 2; ++kk)
                qa[kk] = *(const bf16x8*)((char*)Qs + (r0 + ln) * 128
                           + ((kk * 64 + lg * 16) ^ ((ln & 7) << 4)));

            float m = -INFINITY, lsum = 0.f;
            f32x4 o[4];
#pragma unroll
            for (int f = 0; f < 4; ++f) o[f] = (f32x4){0.f, 0.f, 0.f, 0.f};

            const int nkt = (g >> 1) + 1;
            for (int kt = 0; kt < nkt; ++kt) {
                const int n0 = kt * 32;

                f32x4 s2[2];
#pragma unroll
                for (int h = 0; h < 2; ++h) {
                    const int key = n0 + 16 * h + ln;
                    bf16x8 kb0 = *(const bf16x8*)((char*)Ks + key * 128
                                   + ((lg * 16) ^ ((key & 7) << 4)));
                    bf16x8 kb1 = *(const bf16x8*)((char*)Ks + key * 128
                                   + ((64 + lg * 16) ^ ((key & 7) << 4)));
                    f32x4 z = (f32x4){0.f, 0.f, 0.f, 0.f};
                    z = __builtin_amdgcn_mfma_f32_16x16x32_bf16(kb0, qa[0], z, 0, 0, 0);
                    s2[h] = __builtin_amdgcn_mfma_f32_16x16x32_bf16(kb1, qa[1], z, 0, 0, 0);
                }

                float sm[2][4];
#pragma unroll
                for (int h = 0; h < 2; ++h)
#pragma unroll
                    for (int r = 0; r < 4; ++r) {
                        const int key = n0 + 16 * h + lg * 4 + r;
                        float v = s2[h][r] * scale;
                        sm[h][r] = (qrow >= key) ? v : -INFINITY;
                    }

                float tmax = fmaxf(fmaxf(fmaxf(sm[0][0], sm[0][1]), fmaxf(sm[0][2], sm[0][3])),
                                   fmaxf(fmaxf(sm[1][0], sm[1][1]), fmaxf(sm[1][2], sm[1][3])));
                tmax = fmaxf(tmax, __shfl_xor(tmax, 16, 64));
                tmax = fmaxf(tmax, __shfl_xor(tmax, 32, 64));

                // T13 defer-max: only rescale when the running max actually grows
                if (!__all(tmax <= m)) {
                    const float mn = fmaxf(m, tmax);
                    const float fac = __expf(m - mn);
                    lsum *= fac;
                    m = mn;
#pragma unroll
                    for (int f = 0; f < 4; ++f) o[f] *= fac;
                }

                float p[2][4];
                float rs = 0.f;
#pragma unroll
                for (int h = 0; h < 2; ++h)
#pragma unroll
                    for (int r = 0; r < 4; ++r) {
                        p[h][r] = __expf(sm[h][r] - m);
                        rs += p[h][r];
                    }
                rs += __shfl_xor(rs, 16, 64);
                rs += __shfl_xor(rs, 32, 64);
                lsum += rs;

                // P -> LDS: row = q-row(ln), col = key (packed bf16 pairs)
#pragma unroll
                for (int h = 0; h < 2; ++h)
#pragma unroll
                    for (int rp = 0; rp < 2; ++rp) {
                        unsigned pk = (unsigned)f2bf(p[h][2 * rp])
                                    | ((unsigned)f2bf(p[h][2 * rp + 1]) << 16);
                        *(unsigned*)(Pl + ln * 40 + 16 * h + lg * 4 + 2 * rp) = pk;
                    }

                bf16x8 pa = *(const bf16x8*)(Pl + ln * 40 + lg * 8);

                // PV: A = V^T (rows = features), B = P (cols = q-rows)
#pragma unroll
                for (int f = 0; f < 4; ++f) {
                    const int vr = f * 16 + ln;
                    bf16x8 vb = *(const bf16x8*)((char*)Vts + vr * 512
                                  + ((n0 * 2 + lg * 16) ^ ((ln & 7) << 4)));
                    o[f] = __builtin_amdgcn_mfma_f32_16x16x32_bf16(vb, pa, o[f], 0, 0, 0);
                }
            }

            // epilogue: lane owns row qrow, cols f*16 + lg*4 .. +3 -> float4
            const float inv = 1.f / lsum;
#pragma unroll
            for (int f = 0; f < 4; ++f) {
                float4 sv;
                sv.x = o[f][0] * inv; sv.y = o[f][1] * inv;
                sv.z = o[f][2] * inv; sv.w = o[f][3] * inv;
                *(float4*)(outb + (size_t)qrow * HS_ + f * 16 + lg * 4) = sv;
            }
        }
        __syncthreads();   // phase-2 LDS reads done before next batch's W gll
    }
}

extern "C" void kernel_launch(void* const* d_in, const int* in_sizes, int n_in,
                              void* d_out, int out_size, void* d_ws, size_t ws_size,
                              hipStream_t stream) {
    const float* x  = (const float*)d_in[0];
    const float* Wq = (const float*)d_in[1];
    const float* Wk = (const float*)d_in[2];
    const float* Wv = (const float*)d_in[3];
    float* out = (float*)d_out;

    unsigned short* WTf = (unsigned short*)d_ws;     // 96 KB

    wt_kernel<<<24, 256, 0, stream>>>(Wq, Wk, Wv, WTf);
    fused_kernel<<<256, 1024, 0, stream>>>(x, WTf, out);
}

// Round 14
// 56.968 us; speedup vs baseline: 1.9000x; 1.9000x over previous
//
#include <hip/hip_runtime.h>
#include <hip/hip_bf16.h>
#include <cstdint>
#include <cmath>

#define B_ 512
#define T_ 256
#define C_ 256
#define HS_ 64

typedef short bf16x8 __attribute__((ext_vector_type(8)));
typedef float f32x4 __attribute__((ext_vector_type(4)));

static __device__ __forceinline__ unsigned short f2bf(float f) {
    union { float f; unsigned int u; } v; v.f = f;
    unsigned int r = v.u + 0x7fffu + ((v.u >> 16) & 1u);
    return (unsigned short)(r >> 16);
}

static __device__ __forceinline__ uint2 pack4(f32x4 a) {
    uint2 r;
    r.x = (unsigned)f2bf(a[0]) | ((unsigned)f2bf(a[1]) << 16);
    r.y = (unsigned)f2bf(a[2]) | ((unsigned)f2bf(a[3]) << 16);
    return r;
}

// ---- Kernel 0: W -> pre-fragmented bf16 WTf.
// fb = fid*8 + kap ; fid = ws*4+f ; WTf[fb*512 + l*8 + j] = W_ws[kap*32+(l>>4)*8+j][f*16+(l&15)]
__global__ void wt_kernel(const float* __restrict__ Wq, const float* __restrict__ Wk,
                          const float* __restrict__ Wv, unsigned short* __restrict__ WTf) {
    int idx = blockIdx.x * 256 + threadIdx.x;
    if (idx >= 96 * 64) return;
    int fb = idx >> 6;
    int l = idx & 63;
    int ws = fb >> 5;
    int rem = fb & 31;
    int f = rem >> 3;
    int kap = rem & 7;
    const float* W = (ws == 0) ? Wq : ((ws == 1) ? Wk : Wv);
    unsigned short o[8];
#pragma unroll
    for (int j = 0; j < 8; ++j) {
        int k = kap * 32 + (l >> 4) * 8 + j;
        int n = f * 16 + (l & 15);
        o[j] = f2bf(W[k * HS_ + n]);
    }
    *(ulonglong2*)(WTf + (size_t)idx * 8) = *(ulonglong2*)o;
}

// Phase-2 granule LUT: wave w (SIMD = w%4) -> granule.
// KVBLK=64: nkt64(g) = (g>>2)+1; per-SIMD sums: {15,13,1,3}=10, {14,12,0,2}=10,
// {11,10,4,5}=10, {9,8,6,7}=10 — balanced.
__device__ __constant__ const int g_lut[16] = {15,14,11,9, 13,12,10,8, 1,0,4,6, 3,2,5,7};

// ---- Fused kernel: one block per batch. 1024 threads / 16 waves. 160 KB LDS.
// [0,96K):  W (phase 1) -> Q[32K)/K[32K)/Vt[32K) (phase 2)
// [96K,160K): x slab buffer (phase 2: per-wave P tiles, stride 144B)
__global__ __launch_bounds__(1024, 4)
void fused_kernel(const float* __restrict__ x, const unsigned short* __restrict__ WTf,
                  float* __restrict__ out) {
    __shared__ __align__(16) char smem[163840];
    unsigned short* Qs  = (unsigned short*)(smem);
    unsigned short* Ks  = (unsigned short*)(smem + 32768);
    unsigned short* Vts = (unsigned short*)(smem + 65536);
    char* xbuf = smem + 98304;

    const int tid = threadIdx.x;
    const int w = tid >> 6, l = tid & 63, ln = l & 15, lg = l >> 4;
    const int b = blockIdx.x;
    const float* xb = x + (size_t)b * (T_ * C_);
    const int ttp = w & 3;          // tile-pair: tiles 2*ttp, 2*ttp+1
    const int fg  = w >> 2;         // fid-group: fids fg*3 .. fg*3+2
    const float scale = 0.0625f;    // C^-0.5

    // ---- prologue: W -> LDS (linear dest), 96 KB in 6 passes ----
#pragma unroll
    for (int r = 0; r < 6; ++r)
        __builtin_amdgcn_global_load_lds(
            (const __attribute__((address_space(1))) void*)((const char*)WTf + r * 16384 + tid * 16),
            (__attribute__((address_space(3))) void*)(smem + r * 16384 + tid * 16), 16, 0, 0);

    float4 st[8];
#pragma unroll
    for (int i = 0; i < 8; ++i)
        st[i] = *(const float4*)(xb + (size_t)(i * 1024 + tid) * 4);

    uint2 h0[6], h1[6];

#define DS_WRITE_SLAB() do { \
    _Pragma("unroll") \
    for (int i_ = 0; i_ < 8; ++i_) { \
        const int fidx_ = i_ * 1024 + tid, row_ = fidx_ >> 6, c4_ = (fidx_ & 63) * 4; \
        ushort4 hh_; \
        hh_.x = f2bf(st[i_].x); hh_.y = f2bf(st[i_].y); \
        hh_.z = f2bf(st[i_].z); hh_.w = f2bf(st[i_].w); \
        *(ushort4*)(xbuf + row_ * 512 + ((c4_ * 2) ^ ((row_ & 7) << 4))) = hh_; \
    } \
} while (0)

#define SLAB_COMPUTE(H) do { \
    f32x4 acc_[6]; \
    _Pragma("unroll") \
    for (int k_ = 0; k_ < 6; ++k_) acc_[k_] = (f32x4){0.f, 0.f, 0.f, 0.f}; \
    _Pragma("unroll") \
    for (int kap_ = 0; kap_ < 8; ++kap_) { \
        bf16x8 bfr_[3]; \
        _Pragma("unroll") \
        for (int j_ = 0; j_ < 3; ++j_) \
            bfr_[j_] = *(const bf16x8*)(smem + (size_t)((fg * 3 + j_) * 8 + kap_) * 1024 + l * 16); \
        _Pragma("unroll") \
        for (int tt_ = 0; tt_ < 2; ++tt_) { \
            const int R_ = (2 * ttp + tt_) * 16 + ln; \
            bf16x8 afr_ = *(const bf16x8*)(xbuf + R_ * 512 \
                           + ((kap_ * 64 + lg * 16) ^ ((R_ & 7) << 4))); \
            _Pragma("unroll") \
            for (int j_ = 0; j_ < 3; ++j_) \
                acc_[tt_ * 3 + j_] = __builtin_amdgcn_mfma_f32_16x16x32_bf16( \
                    bfr_[j_], afr_, acc_[tt_ * 3 + j_], 0, 0, 0); \
        } \
    } \
    _Pragma("unroll") \
    for (int k_ = 0; k_ < 6; ++k_) H[k_] = pack4(acc_[k_]); \
} while (0)

    // ---- slab 0 ----
    DS_WRITE_SLAB();            // vmcnt wait on st drains W gll too (FIFO)
    __syncthreads();
#pragma unroll
    for (int i = 0; i < 8; ++i)    // slab-1 prefetch under slab-0 compute
        st[i] = *(const float4*)(xb + 32768 + (size_t)(i * 1024 + tid) * 4);
    SLAB_COMPUTE(h0);
    __syncthreads();

    // ---- slab 1 ----
    DS_WRITE_SLAB();
    __syncthreads();
    SLAB_COMPUTE(h1);
    __syncthreads();            // all W-lds reads done; region reusable

    // ---- phase 1.5: QKV regs -> LDS (overwrites W region) ----
#pragma unroll
    for (int s = 0; s < 2; ++s) {
#pragma unroll
        for (int tt = 0; tt < 2; ++tt)
#pragma unroll
            for (int j = 0; j < 3; ++j) {
                uint2 hv = s ? h1[tt * 3 + j] : h0[tt * 3 + j];
                const int token = s * 128 + (2 * ttp + tt) * 16 + ln;
                const int fid = fg * 3 + j, f = fid & 3;
                if (fid < 8) {
                    unsigned short* base_ = (fid < 4) ? Qs : Ks;
                    *(uint2*)((char*)base_ + token * 128
                              + ((f * 32 + lg * 8) ^ ((token & 7) << 4))) = hv;
                } else {
                    unsigned short v4[4] = {
                        (unsigned short)(hv.x & 0xffff), (unsigned short)(hv.x >> 16),
                        (unsigned short)(hv.y & 0xffff), (unsigned short)(hv.y >> 16)};
#pragma unroll
                    for (int i = 0; i < 4; ++i) {
                        const int vr = f * 16 + lg * 4 + i;
                        *(unsigned short*)((char*)Vts + vr * 512
                              + ((token * 2) ^ ((vr & 7) << 4))) = v4[i];
                    }
                }
            }
    }
    __syncthreads();

    // ---- phase 2: causal attention, swapped-QK^T, KVBLK=64; wave = ONE granule ----
    unsigned short* Pl = (unsigned short*)(xbuf + w * 2560);   // [16 rows][72 shorts]
    float* outb = out + (size_t)b * (T_ * HS_);

    {
        const int g = g_lut[w];
        const int r0 = g * 16;
        const int qrow = r0 + ln;

        bf16x8 qa[2];
#pragma unroll
        for (int kk = 0; kk < 2; ++kk)
            qa[kk] = *(const bf16x8*)((char*)Qs + (r0 + ln) * 128
                       + ((kk * 64 + lg * 16) ^ ((ln & 7) << 4)));

        float m = -INFINITY, lsum = 0.f;
        f32x4 o[4];
#pragma unroll
        for (int f = 0; f < 4; ++f) o[f] = (f32x4){0.f, 0.f, 0.f, 0.f};

        const int nkt = (g >> 2) + 1;
        for (int kt = 0; kt < nkt; ++kt) {
            const int n0 = kt * 64;

            // QK^T: 4 halves of 16 keys, K=64 via 2 chained MFMAs each
            f32x4 s2[4];
            __builtin_amdgcn_s_setprio(1);
#pragma unroll
            for (int h = 0; h < 4; ++h) {
                const int key = n0 + 16 * h + ln;
                bf16x8 kb0 = *(const bf16x8*)((char*)Ks + key * 128
                               + ((lg * 16) ^ ((key & 7) << 4)));
                bf16x8 kb1 = *(const bf16x8*)((char*)Ks + key * 128
                               + ((64 + lg * 16) ^ ((key & 7) << 4)));
                f32x4 z = (f32x4){0.f, 0.f, 0.f, 0.f};
                z = __builtin_amdgcn_mfma_f32_16x16x32_bf16(kb0, qa[0], z, 0, 0, 0);
                s2[h] = __builtin_amdgcn_mfma_f32_16x16x32_bf16(kb1, qa[1], z, 0, 0, 0);
            }
            __builtin_amdgcn_s_setprio(0);

            // mask + scale; all 16 scores belong to THIS lane's q-row
            float sm[4][4];
#pragma unroll
            for (int h = 0; h < 4; ++h)
#pragma unroll
                for (int r = 0; r < 4; ++r) {
                    const int key = n0 + 16 * h + lg * 4 + r;
                    float v = s2[h][r] * scale;
                    sm[h][r] = (qrow >= key) ? v : -INFINITY;
                }

            // in-lane max of 16, then 2-step reduce over the 4 lg-duplicates
            float tmax = sm[0][0];
#pragma unroll
            for (int h = 0; h < 4; ++h)
#pragma unroll
                for (int r = 0; r < 4; ++r) tmax = fmaxf(tmax, sm[h][r]);
            tmax = fmaxf(tmax, __shfl_xor(tmax, 16, 64));
            tmax = fmaxf(tmax, __shfl_xor(tmax, 32, 64));

            // T13 defer-max: only rescale when the running max actually grows
            if (!__all(tmax <= m)) {
                const float mn = fmaxf(m, tmax);
                const float fac = __expf(m - mn);
                lsum *= fac;
                m = mn;
#pragma unroll
                for (int f = 0; f < 4; ++f) o[f] *= fac;
            }

            float p[4][4];
            float rs = 0.f;
#pragma unroll
            for (int h = 0; h < 4; ++h)
#pragma unroll
                for (int r = 0; r < 4; ++r) {
                    p[h][r] = __expf(sm[h][r] - m);
                    rs += p[h][r];
                }
            rs += __shfl_xor(rs, 16, 64);
            rs += __shfl_xor(rs, 32, 64);
            lsum += rs;

            // P -> LDS: row = q-row(ln), col = key-n0 (packed bf16 pairs)
#pragma unroll
            for (int h = 0; h < 4; ++h)
#pragma unroll
                for (int rp = 0; rp < 2; ++rp) {
                    unsigned pk = (unsigned)f2bf(p[h][2 * rp])
                                | ((unsigned)f2bf(p[h][2 * rp + 1]) << 16);
                    *(unsigned*)(Pl + ln * 72 + 16 * h + lg * 4 + 2 * rp) = pk;
                }

            bf16x8 pa[2];
#pragma unroll
            for (int c = 0; c < 2; ++c)
                pa[c] = *(const bf16x8*)(Pl + ln * 72 + c * 32 + lg * 8);

            // PV: A = V^T (rows = features), B = P (cols = q-rows); 2 key-chunks
            __builtin_amdgcn_s_setprio(1);
#pragma unroll
            for (int f = 0; f < 4; ++f) {
                const int vr = f * 16 + ln;
#pragma unroll
                for (int c = 0; c < 2; ++c) {
                    bf16x8 vb = *(const bf16x8*)((char*)Vts + vr * 512
                                  + (((n0 + c * 32) * 2 + lg * 16) ^ ((vr & 7) << 4)));
                    o[f] = __builtin_amdgcn_mfma_f32_16x16x32_bf16(vb, pa[c], o[f], 0, 0, 0);
                }
            }
            __builtin_amdgcn_s_setprio(0);
        }

        // epilogue: lane owns row qrow, cols f*16 + lg*4 .. +3 -> float4
        const float inv = 1.f / lsum;
#pragma unroll
        for (int f = 0; f < 4; ++f) {
            float4 sv;
            sv.x = o[f][0] * inv; sv.y = o[f][1] * inv;
            sv.z = o[f][2] * inv; sv.w = o[f][3] * inv;
            *(float4*)(outb + (size_t)qrow * HS_ + f * 16 + lg * 4) = sv;
        }
    }
}

extern "C" void kernel_launch(void* const* d_in, const int* in_sizes, int n_in,
                              void* d_out, int out_size, void* d_ws, size_t ws_size,
                              hipStream_t stream) {
    const float* x  = (const float*)d_in[0];
    const float* Wq = (const float*)d_in[1];
    const float* Wk = (const float*)d_in[2];
    const float* Wv = (const float*)d_in[3];
    float* out = (float*)d_out;

    unsigned short* WTf = (unsigned short*)d_ws;     // 96 KB

    wt_kernel<<<24, 256, 0, stream>>>(Wq, Wk, Wv, WTf);
    fused_kernel<<<B_, 1024, 0, stream>>>(x, WTf, out);
}